// Round 23
// baseline (302.689 us; speedup 1.0000x reference)
//
#include <hip/hip_runtime.h>

typedef __attribute__((ext_vector_type(8))) short bf16x8;
typedef __attribute__((ext_vector_type(4))) float f32x4;

#define KTOT 110592   // 4096*27
#define KS2  64       // conv K-split blocks
#define KCH  1728     // KTOT/KS2
#define NIT  54       // KCH/32

__device__ __forceinline__ unsigned short f2bf(float f) {
  unsigned int u = __float_as_uint(f);
  unsigned int r = u + 0x7FFFu + ((u >> 16) & 1u);
  return (unsigned short)(r >> 16);
}
__device__ __forceinline__ float bf2f(unsigned short u) {
  return __uint_as_float((unsigned int)u << 16);
}
__device__ __forceinline__ float wred_sum(float v) {
#pragma unroll
  for (int m = 32; m > 0; m >>= 1) v += __shfl_xor(v, m, 64);
  return v;
}
__device__ __forceinline__ float wred_max(float v) {
#pragma unroll
  for (int m = 32; m > 0; m >>= 1) v = fmaxf(v, __shfl_xor(v, m, 64));
  return v;
}
__device__ __forceinline__ void gld16(const void* g, void* l) {
  __builtin_amdgcn_global_load_lds((const __attribute__((address_space(1))) void*)g,
                                   (__attribute__((address_space(3))) void*)l, 16, 0, 0);
}

// ---------- K0: FUSED dwt (blocks 0..107) + weight transposes (blocks 108..299) (r20) ----------
__global__ __launch_bounds__(256) void k_front2(const float* __restrict__ x,
                                                const float* __restrict__ qkvw,
                                                const float* __restrict__ pw,
                                                float* __restrict__ xd,
                                                unsigned short* __restrict__ qwT,
                                                unsigned short* __restrict__ pwT) {
  __shared__ float tile[64][68];
  int t = threadIdx.x;
  int bid = blockIdx.x;

  if (bid < 108) {
    int b = bid / 27, p = bid % 27;
    int pd = p / 9, ph = (p / 3) % 3, pw3 = p % 3;
    const float s3 = 0.35355339059327373f;
#pragma unroll
    for (int cc = 0; cc < 2; cc++) {
      int c = t + cc * 256;
      const float* xb = x + (size_t)b * 216 * 512 + c;
#define XL(ed, eh, ew) xb[((2 * pd + (ed)) * 36 + (2 * ph + (eh)) * 6 + (2 * pw3 + (ew))) * 512]
      float v000 = XL(0, 0, 0), v001 = XL(0, 0, 1), v010 = XL(0, 1, 0), v011 = XL(0, 1, 1);
      float v100 = XL(1, 0, 0), v101 = XL(1, 0, 1), v110 = XL(1, 1, 0), v111 = XL(1, 1, 1);
#undef XL
      float lo00 = v000 + v001, hi00 = v000 - v001;
      float lo01 = v010 + v011, hi01 = v010 - v011;
      float lo10 = v100 + v101, hi10 = v100 - v101;
      float lo11 = v110 + v111, hi11 = v110 - v111;
      float ll0 = lo00 + lo01, lh0 = hi00 + hi01, hl0 = lo00 - lo01, hh0 = hi00 - hi01;
      float ll1 = lo10 + lo11, lh1 = hi10 + hi11, hl1 = lo10 - lo11, hh1 = hi10 - hi11;
      size_t base = (size_t)b * 110592 + (size_t)c * 27 + p;
      xd[base + 0 * 13824] = (ll0 + ll1) * s3;
      xd[base + 1 * 13824] = (lh0 + lh1) * s3;
      xd[base + 2 * 13824] = (hl0 + hl1) * s3;
      xd[base + 3 * 13824] = (hh0 + hh1) * s3;
      xd[base + 4 * 13824] = (ll0 - ll1) * s3;
      xd[base + 5 * 13824] = (lh0 - lh1) * s3;
      xd[base + 6 * 13824] = (hl0 - hl1) * s3;
      xd[base + 7 * 13824] = (hh0 - hh1) * s3;
    }
    return;
  }

  int idx = bid - 108;
  int bx = idx % 24;
  int n0 = (idx / 24) * 64;
  const float* src;
  unsigned short* dst;
  int rs, K, k0;
  if (bx < 8) { src = qkvw; dst = qwT; rs = 1536; K = 512; k0 = bx * 64; }
  else        { src = pw;   dst = pwT; rs = 512;  K = 1024; k0 = (bx - 8) * 64; }
  int kr = t >> 4, n4 = (t & 15) * 4;
#pragma unroll
  for (int i = 0; i < 4; i++) {
    int k = kr + i * 16;
    float4 v = *(const float4*)&src[(size_t)(k0 + k) * rs + n0 + n4];
    *(float4*)&tile[k][n4] = v;
  }
  __syncthreads();
  int nr = t >> 4, k4 = (t & 15) * 4;
#pragma unroll
  for (int i = 0; i < 4; i++) {
    int n = nr + i * 16;
    ushort4 o;
    o.x = f2bf(tile[k4 + 0][n]);
    o.y = f2bf(tile[k4 + 1][n]);
    o.z = f2bf(tile[k4 + 2][n]);
    o.w = f2bf(tile[k4 + 3][n]);
    *(ushort4*)&dst[(size_t)(n0 + n) * K + k0 + k4] = o;
  }
}

// ---------- K1: MFMA GEMM 64x64, 2-buffer pipelined (r20) ----------
__global__ __launch_bounds__(256) void k_gemm64(const float* __restrict__ A0,
                                                const float* __restrict__ A1,
                                                const unsigned short* __restrict__ BT,
                                                const float* __restrict__ bias,
                                                float* __restrict__ C, int K) {
  __shared__ __align__(16) unsigned short Ab[2][4096];
  __shared__ __align__(16) unsigned short Bb[2][4096];
  int t = threadIdx.x, l = t & 63, w = t >> 6;
  int wm = w & 1, wn = w >> 1;
  int n0 = blockIdx.x * 64, m0 = blockIdx.y * 64;
  int row = w * 16 + (l & 15);
  int kq = (l >> 4) * 8;
  int mg = m0 + row;
  bool mok = mg < 864;
  const unsigned short* pBt = BT + (size_t)(n0 + row) * K + kq;

#define GSTAGE(c, kk0)                                                      \
  do {                                                                      \
    gld16(pBt + (kk0), &Bb[c][t * 8]);                                      \
    gld16(pBt + (kk0) + 32, &Bb[c][2048 + t * 8]);                          \
    _Pragma("unroll") for (int s = 0; s < 2; s++) {                         \
      int ks = (kk0) + s * 32 + kq;                                         \
      float v[8] = {0.f, 0.f, 0.f, 0.f, 0.f, 0.f, 0.f, 0.f};                \
      if (mok) {                                                            \
        const float* sp = (ks < 512) ? (A0 + (size_t)mg * 512 + ks)         \
                                     : (A1 + (size_t)mg * 512 + (ks - 512));\
        float4 a = *(const float4*)sp;                                      \
        float4 b = *(const float4*)(sp + 4);                                \
        v[0] = a.x; v[1] = a.y; v[2] = a.z; v[3] = a.w;                     \
        v[4] = b.x; v[5] = b.y; v[6] = b.z; v[7] = b.w;                     \
      }                                                                     \
      union { unsigned short u[8]; bf16x8 h; } pk;                          \
      _Pragma("unroll") for (int e = 0; e < 8; e++) pk.u[e] = f2bf(v[e]);   \
      *(bf16x8*)&Ab[c][s * 2048 + t * 8] = pk.h;                            \
    }                                                                       \
  } while (0)

  f32x4 acc[2][2];
#pragma unroll
  for (int i = 0; i < 2; i++)
#pragma unroll
    for (int j = 0; j < 2; j++) acc[i][j] = (f32x4){0.f, 0.f, 0.f, 0.f};

  GSTAGE(0, 0);
  int cur = 0;
  for (int k0 = 0; k0 < K; k0 += 64) {
    __syncthreads();
    if (k0 + 64 < K) GSTAGE(cur ^ 1, k0 + 64);
#pragma unroll
    for (int kk = 0; kk < 2; kk++) {
      bf16x8 af[2], bf[2];
#pragma unroll
      for (int i = 0; i < 2; i++)
        af[i] = *(const bf16x8*)&Ab[cur][((kk * 4 + wm * 2 + i) * 64 + l) * 8];
#pragma unroll
      for (int j = 0; j < 2; j++)
        bf[j] = *(const bf16x8*)&Bb[cur][((kk * 4 + wn * 2 + j) * 64 + l) * 8];
#pragma unroll
      for (int i = 0; i < 2; i++)
#pragma unroll
        for (int j = 0; j < 2; j++)
          acc[i][j] = __builtin_amdgcn_mfma_f32_16x16x32_bf16(af[i], bf[j], acc[i][j], 0, 0, 0);
    }
    cur ^= 1;
  }
#undef GSTAGE
#pragma unroll
  for (int i = 0; i < 2; i++)
#pragma unroll
    for (int j = 0; j < 2; j++) {
      int n = n0 + wn * 32 + j * 16 + (l & 15);
      float bb = bias ? bias[n] : 0.f;
#pragma unroll
      for (int r = 0; r < 4; r++) {
        int m = m0 + wm * 32 + i * 16 + (l >> 4) * 4 + r;
        if (m < 864) C[(size_t)m * 512 + n] = acc[i][j][r] + bb;
      }
    }
}

// ---------- K3: im2col, 8 bf16 per thread (r8) ----------
__global__ __launch_bounds__(256) void k_im2col8(const float* __restrict__ xd,
                                                 unsigned short* __restrict__ A) {
  __shared__ int offtab[27];
  int m = blockIdx.y, t = threadIdx.x;
  if (m < 108 && t < 27) {
    int po = m % 27;
    int od = po / 9, oh = (po / 3) % 3, ow = po % 3;
    int kd = t / 9, kh = (t / 3) % 3, kw = t % 3;
    int id = od + kd - 1, ih = oh + kh - 1, iw = ow + kw - 1;
    offtab[t] = ((unsigned)id < 3u && (unsigned)ih < 3u && (unsigned)iw < 3u)
                    ? (id * 9 + ih * 3 + iw) : -1;
  }
  __syncthreads();
  int k0 = (blockIdx.x * 256 + t) * 8;
  union { unsigned short u[8]; uint4 q; } ov;
#pragma unroll
  for (int e = 0; e < 8; e++) ov.u[e] = 0;
  if (m < 108) {
    int b = m / 27;
    int ic = k0 / 27;
    int tt = k0 - ic * 27;
    const float* src = xd + ((size_t)b * 4096 + ic) * 27;
#pragma unroll
    for (int e = 0; e < 8; e++) {
      int o = offtab[tt];
      float v = (o >= 0) ? src[o] : 0.f;
      ov.u[e] = f2bf(v);
      if (++tt == 27) { tt = 0; src += 27; }
    }
  }
  *(uint4*)&A[(size_t)m * KTOT + k0] = ov.q;
}

// ---------- K4: FUSED conv4 + qgemm; conv partials stored as BF16 (r22 champion) ----------
__global__ __launch_bounds__(256, 2) void k_convq(const unsigned short* __restrict__ Ag,
                                                  const float* __restrict__ W,
                                                  unsigned short* __restrict__ fpart,
                                                  const float* __restrict__ x,
                                                  const unsigned short* __restrict__ qwT,
                                                  float* __restrict__ q) {
  __shared__ __align__(16) char smem[73728];
  int t = threadIdx.x, l = t & 63, w = t >> 6;
  int bid = blockIdx.x;

  if (bid >= 512) {
    unsigned short* Ab = (unsigned short*)smem;          // 8KB
    unsigned short* Bb = (unsigned short*)(smem + 8192); // 8KB
    int g = bid - 512;  // 0..111
    int n0 = (g & 7) * 64, m0 = (g >> 3) * 64;
    int wm = w & 1, wn = w >> 1;
    int row = w * 16 + (l & 15);
    int kq = (l >> 4) * 8;
    int mg = m0 + row;
    bool mok = mg < 864;
    const unsigned short* pBt = qwT + (size_t)(n0 + row) * 512 + kq;
    f32x4 acc[2][2];
#pragma unroll
    for (int i = 0; i < 2; i++)
#pragma unroll
      for (int j = 0; j < 2; j++) acc[i][j] = (f32x4){0.f, 0.f, 0.f, 0.f};
    for (int k0 = 0; k0 < 512; k0 += 64) {
      __syncthreads();
      gld16(pBt + k0, &Bb[t * 8]);
      gld16(pBt + k0 + 32, &Bb[2048 + t * 8]);
#pragma unroll
      for (int s = 0; s < 2; s++) {
        int ks = k0 + s * 32 + kq;
        float v[8] = {0.f, 0.f, 0.f, 0.f, 0.f, 0.f, 0.f, 0.f};
        if (mok) {
          const float* sp = x + (size_t)mg * 512 + ks;
          float4 a = *(const float4*)sp;
          float4 b = *(const float4*)(sp + 4);
          v[0] = a.x; v[1] = a.y; v[2] = a.z; v[3] = a.w;
          v[4] = b.x; v[5] = b.y; v[6] = b.z; v[7] = b.w;
        }
        union { unsigned short u[8]; bf16x8 h; } pk;
#pragma unroll
        for (int e = 0; e < 8; e++) pk.u[e] = f2bf(v[e]);
        *(bf16x8*)&Ab[s * 2048 + t * 8] = pk.h;
      }
      __syncthreads();
#pragma unroll
      for (int kk = 0; kk < 2; kk++) {
        bf16x8 af[2], bf[2];
#pragma unroll
        for (int i = 0; i < 2; i++)
          af[i] = *(const bf16x8*)&Ab[((kk * 4 + wm * 2 + i) * 64 + l) * 8];
#pragma unroll
        for (int j = 0; j < 2; j++)
          bf[j] = *(const bf16x8*)&Bb[((kk * 4 + wn * 2 + j) * 64 + l) * 8];
#pragma unroll
        for (int i = 0; i < 2; i++)
#pragma unroll
          for (int j = 0; j < 2; j++)
            acc[i][j] = __builtin_amdgcn_mfma_f32_16x16x32_bf16(af[i], bf[j], acc[i][j], 0, 0, 0);
      }
    }
#pragma unroll
    for (int i = 0; i < 2; i++)
#pragma unroll
      for (int j = 0; j < 2; j++) {
        int n = n0 + wn * 32 + j * 16 + (l & 15);
#pragma unroll
        for (int r = 0; r < 4; r++) {
          int m = m0 + wm * 32 + i * 16 + (l >> 4) * 4 + r;
          if (m < 864) q[(size_t)m * 512 + n] = acc[i][j][r];
        }
      }
    return;
  }

  typedef unsigned short (*AbufT)[4096];
  typedef float (*BbufT)[4096];
  AbufT Abuf = (AbufT)smem;            // 3 x 8KB = 24KB
  BbufT Bbuf = (BbufT)(smem + 24576);  // 3 x 16KB = 48KB
  int wm = w & 1, wn = w >> 1;
  int oc0 = (bid & 7) * 128;
  int ks = bid >> 3;
  int kbase = ks * KCH;
  int kq = (l >> 4) * 8;

  const unsigned short* pA0 = Ag + (size_t)(w * 16 + (l & 15)) * KTOT + kbase + kq;
  const unsigned short* pA1 = Ag + (size_t)((w + 4) * 16 + (l & 15)) * KTOT + kbase + kq;
  const float* pB0 = W + (size_t)(oc0 + w * 16 + (l & 15)) * KTOT + kbase + kq;
  const float* pB1 = W + (size_t)(oc0 + (w + 4) * 16 + (l & 15)) * KTOT + kbase + kq;
  const float* pB2 = pB0 + 4;
  const float* pB3 = pB1 + 4;

#define STG(c, s)                                   \
  do {                                              \
    int ko = (s) * 32;                              \
    gld16(pA0 + ko, &Abuf[c][t * 8]);               \
    gld16(pA1 + ko, &Abuf[c][2048 + t * 8]);        \
    gld16(pB0 + ko, &Bbuf[c][t * 4]);               \
    gld16(pB1 + ko, &Bbuf[c][1024 + t * 4]);        \
    gld16(pB2 + ko, &Bbuf[c][2048 + t * 4]);        \
    gld16(pB3 + ko, &Bbuf[c][3072 + t * 4]);        \
  } while (0)

  f32x4 acc[4][4];
#pragma unroll
  for (int i = 0; i < 4; i++)
#pragma unroll
    for (int j = 0; j < 4; j++) acc[i][j] = (f32x4){0.f, 0.f, 0.f, 0.f};

#define CMP(c)                                                                     \
  do {                                                                             \
    bf16x8 av[4];                                                                  \
    _Pragma("unroll") for (int i = 0; i < 4; i++)                                  \
        av[i] = *(const bf16x8*)&Abuf[c][((wm * 4 + i) * 64 + l) * 8];             \
    bf16x8 bv[4];                                                                  \
    _Pragma("unroll") for (int j = 0; j < 4; j++) {                                \
      f32x4 lo = *(const f32x4*)&Bbuf[c][((wn * 4 + j) * 64 + l) * 4];             \
      f32x4 hi = *(const f32x4*)&Bbuf[c][2048 + ((wn * 4 + j) * 64 + l) * 4];      \
      union { unsigned short u[8]; bf16x8 h; } pk;                                 \
      _Pragma("unroll") for (int e = 0; e < 4; e++) {                              \
        pk.u[e] = f2bf(lo[e]); pk.u[4 + e] = f2bf(hi[e]);                          \
      }                                                                            \
      bv[j] = pk.h;                                                                \
    }                                                                              \
    _Pragma("unroll") for (int i = 0; i < 4; i++)                                  \
        _Pragma("unroll") for (int j = 0; j < 4; j++)                              \
            acc[i][j] = __builtin_amdgcn_mfma_f32_16x16x32_bf16(av[i], bv[j],      \
                                                                acc[i][j], 0, 0, 0); \
  } while (0)

#define WAIT6 asm volatile("s_waitcnt vmcnt(6)" ::: "memory")
#define WAIT0 asm volatile("s_waitcnt vmcnt(0)" ::: "memory")

  STG(0, 0);
  STG(1, 1);
  int s = 2;
#pragma unroll 1
  for (int g = 0; g < 17; g++) {  // iters m = 0..50
    WAIT6; __builtin_amdgcn_s_barrier(); STG(2, s); CMP(0); s++;
    WAIT6; __builtin_amdgcn_s_barrier(); STG(0, s); CMP(1); s++;
    WAIT6; __builtin_amdgcn_s_barrier(); STG(1, s); CMP(2); s++;
  }
  WAIT6; __builtin_amdgcn_s_barrier(); STG(2, 53); CMP(0);
  WAIT6; __builtin_amdgcn_s_barrier(); CMP(1);
  WAIT0; __builtin_amdgcn_s_barrier(); CMP(2);
#undef STG
#undef CMP
#undef WAIT6
#undef WAIT0

  int mbase = wm * 64 + (l >> 4) * 4;
  int obase = oc0 + wn * 64 + (l & 15);
#pragma unroll
  for (int i = 0; i < 4; i++) {
    int m = mbase + i * 16;
#pragma unroll
    for (int j = 0; j < 4; j++) {
      int oc = obase + j * 16;
      unsigned short* dst = fpart + ((size_t)ks * 128 + m) * 1024 + oc;
      dst[0] = f2bf(acc[i][j][0]);
      dst[1024] = f2bf(acc[i][j][1]);
      dst[2048] = f2bf(acc[i][j][2]);
      dst[3072] = f2bf(acc[i][j][3]);
    }
  }
}

// ---------- K5a: reduce bf16 K-split + bias + BN + ReLU -> f (B,1024,27) ----------
__global__ __launch_bounds__(256) void k_bnrelu(const unsigned short* __restrict__ fpart,
                                                const float* __restrict__ convb,
                                                const float* __restrict__ bng,
                                                const float* __restrict__ bnb,
                                                const float* __restrict__ bnm,
                                                const float* __restrict__ bnv,
                                                float* __restrict__ f) {
  int ch = blockIdx.x * 256 + threadIdx.x;
  int m = blockIdx.y;
  if (m >= 108) return;
  float s = 0.f;
#pragma unroll 8
  for (int ks = 0; ks < KS2; ks++) s += bf2f(fpart[((size_t)ks * 128 + m) * 1024 + ch]);
  float gs = bng[ch] * rsqrtf(bnv[ch] + 1e-5f);
  float bb = (convb[ch] - bnm[ch]) * gs + bnb[ch];
  float r = fmaxf(s * gs + bb, 0.f);
  int b = m / 27, p = m % 27;
  f[((size_t)b * 1024 + ch) * 27 + p] = r;
}

// ---------- K5b: LayerNorm(27) + kv GEMM + scatter kT, v as BF16 (r19) ----------
__global__ __launch_bounds__(256) void k_lnkv(const float* __restrict__ f,
                                              const float* __restrict__ lng,
                                              const float* __restrict__ lnb,
                                              const float* __restrict__ kvw,
                                              const float* __restrict__ kvb,
                                              unsigned short* __restrict__ kT,
                                              unsigned short* __restrict__ vbuf) {
  __shared__ float g_s[4][28];
  int t = threadIdx.x, w = t >> 6, l = t & 63;
  int row = blockIdx.x * 4 + w;
  int b = row >> 10, ch = row & 1023;
  float val = 0.f;
  if (l < 27) val = f[((size_t)b * 1024 + ch) * 27 + l];
  float x1 = (l < 27) ? val : 0.f;
  float sum = wred_sum(x1);
  float sumsq = wred_sum(x1 * x1);
  float mu = sum * (1.f / 27.f);
  float var = sumsq * (1.f / 27.f) - mu * mu;
  float inv = rsqrtf(var + 1e-5f);
  if (l < 27) g_s[w][l] = (val - mu) * inv * lng[l] + lnb[l];
  __syncthreads();
#pragma unroll
  for (int j = 0; j < 4; j++) {
    int y = j * 64 + l;
    if (y < 216) {
      float acc = kvb[y];
#pragma unroll
      for (int p = 0; p < 27; p++) acc = fmaf(g_s[w][p], kvw[p * 216 + y], acc);
      int cc = ch & 511;
      int flat = cc * 216 + y;
      int n = flat >> 9, hd = flat & 511, h = hd >> 6, d = hd & 63;
      if (ch < 512)
        kT[(((size_t)b * 8 + h) * 64 + d) * 216 + n] = f2bf(acc);
      else
        vbuf[(((size_t)b * 8 + h) * 216 + n) * 64 + d] = f2bf(acc);
    }
  }
}

// ---------- K6: cross-attention, LDS-staged K/V per (b,h) (r21 champion) ----------
__global__ __launch_bounds__(256, 2) void k_attn2(const float* __restrict__ q,
                                                  const unsigned short* __restrict__ kT,
                                                  const unsigned short* __restrict__ vbuf,
                                                  float* __restrict__ o) {
  __shared__ __align__(16) unsigned short ks_s[13824];
  __shared__ __align__(16) unsigned short vs_s[13824];
  __shared__ float q_s[4][64];
  __shared__ float p_s[4][224];
  int t = threadIdx.x, w = t >> 6, l = t & 63;
  int bid = blockIdx.x;
  int b = bid >> 7, h = (bid >> 4) & 7, part = bid & 15;
  int r0 = part * 14;
  const unsigned short* kb = kT + ((size_t)b * 8 + h) * 13824;
  const unsigned short* vb = vbuf + ((size_t)b * 8 + h) * 13824;
  for (int i = t; i < 1728; i += 256) {
    ((uint4*)ks_s)[i] = ((const uint4*)kb)[i];
    ((uint4*)vs_s)[i] = ((const uint4*)vb)[i];
  }
  __syncthreads();
#pragma unroll 1
  for (int it = 0; it < 4; it++) {
    int r = it * 4 + w;
    int n = r0 + r;
    if (r >= 14 || n >= 216) break;
    q_s[w][l] = q[((size_t)b * 216 + n) * 512 + h * 64 + l];
    float sc[4];
#pragma unroll
    for (int j = 0; j < 4; j++) {
      int y = j * 64 + l;
      float s = -1e30f;
      if (y < 216) {
        s = 0.f;
#pragma unroll 8
        for (int d = 0; d < 64; d++) s = fmaf(q_s[w][d], bf2f(ks_s[d * 216 + y]), s);
        s *= 0.125f;
      }
      sc[j] = s;
    }
    float mx = fmaxf(fmaxf(sc[0], sc[1]), fmaxf(sc[2], sc[3]));
    mx = wred_max(mx);
    float e0 = (sc[0] > -1e29f) ? __expf(sc[0] - mx) : 0.f;
    float e1 = (sc[1] > -1e29f) ? __expf(sc[1] - mx) : 0.f;
    float e2 = (sc[2] > -1e29f) ? __expf(sc[2] - mx) : 0.f;
    float e3 = (sc[3] > -1e29f) ? __expf(sc[3] - mx) : 0.f;
    float sum = wred_sum(e0 + e1 + e2 + e3);
    float inv = 1.f / sum;
    if (l < 216) p_s[w][l] = e0 * inv;
    if (64 + l < 216) p_s[w][64 + l] = e1 * inv;
    if (128 + l < 216) p_s[w][128 + l] = e2 * inv;
    if (192 + l < 216) p_s[w][192 + l] = e3 * inv;
    float a0 = 0.f, a1 = 0.f;
#pragma unroll 4
    for (int y = 0; y < 216; y += 2) {
      a0 = fmaf(p_s[w][y + 0], bf2f(vs_s[(y + 0) * 64 + l]), a0);
      a1 = fmaf(p_s[w][y + 1], bf2f(vs_s[(y + 1) * 64 + l]), a1);
    }
    o[((size_t)b * 216 + n) * 512 + h * 64 + l] = a0 + a1;
  }
}

extern "C" void kernel_launch(void* const* d_in, const int* in_sizes, int n_in,
                              void* d_out, int out_size, void* d_ws, size_t ws_size,
                              hipStream_t stream) {
  const float* x = (const float*)d_in[0];
  const float* qkvw = (const float*)d_in[1];
  const float* convw = (const float*)d_in[2];
  const float* convb = (const float*)d_in[3];
  const float* bng = (const float*)d_in[4];
  const float* bnb = (const float*)d_in[5];
  const float* bnm = (const float*)d_in[6];
  const float* bnv = (const float*)d_in[7];
  const float* lng = (const float*)d_in[8];
  const float* lnb = (const float*)d_in[9];
  const float* kvw = (const float*)d_in[10];
  const float* kvb = (const float*)d_in[11];
  const float* pw = (const float*)d_in[12];
  const float* pb = (const float*)d_in[13];
  float* out = (float*)d_out;

  char* ws = (char*)d_ws;
  float* q = (float*)(ws + 0);                              // 1,769,472
  float* xd = (float*)(ws + 1769472);                       // 1,769,472
  unsigned short* A = (unsigned short*)(ws + 3538944);      // 28,311,552
  unsigned short* fpart = (unsigned short*)(ws + 31850496); // 16,777,216 (bf16)
  float* f = (float*)(ws + 48627712);                       // 442,368
  unsigned short* kT = (unsigned short*)(ws + 49070080);    // 884,736 (bf16)
  unsigned short* vbuf = (unsigned short*)(ws + 49954816);  // 884,736 (bf16)
  float* o = (float*)(ws + 50839552);                       // 1,769,472
  unsigned short* qwT = (unsigned short*)(ws + 52609024);   // 524,288
  unsigned short* pwT = (unsigned short*)(ws + 53133312);   // 1,048,576

  // DIAGNOSTIC (r14-style): all non-conv kernels doubled (idempotent).
  // W_small = dur - 221.8; convq measured separately via r7 algebra.
  k_front2<<<300, 256, 0, stream>>>(x, qkvw, pw, xd, qwT, pwT);
  k_front2<<<300, 256, 0, stream>>>(x, qkvw, pw, xd, qwT, pwT);
  k_im2col8<<<dim3(54, 128), 256, 0, stream>>>(xd, A);
  k_im2col8<<<dim3(54, 128), 256, 0, stream>>>(xd, A);
  k_convq<<<624, 256, 0, stream>>>(A, convw, fpart, x, qwT, q);
  k_bnrelu<<<dim3(4, 128), 256, 0, stream>>>(fpart, convb, bng, bnb, bnm, bnv, f);
  k_bnrelu<<<dim3(4, 128), 256, 0, stream>>>(fpart, convb, bng, bnb, bnm, bnv, f);
  k_lnkv<<<1024, 256, 0, stream>>>(f, lng, lnb, kvw, kvb, kT, vbuf);
  k_lnkv<<<1024, 256, 0, stream>>>(f, lng, lnb, kvw, kvb, kT, vbuf);
  k_attn2<<<512, 256, 0, stream>>>(q, kT, vbuf, o);
  k_attn2<<<512, 256, 0, stream>>>(q, kT, vbuf, o);
  k_gemm64<<<dim3(8, 14), 256, 0, stream>>>(o, x, pwT, pb, out, 1024);
  k_gemm64<<<dim3(8, 14), 256, 0, stream>>>(o, x, pwT, pb, out, 1024);
}

// Round 24
// 221.751 us; speedup vs baseline: 1.3650x; 1.3650x over previous
//
#include <hip/hip_runtime.h>

typedef __attribute__((ext_vector_type(8))) short bf16x8;
typedef __attribute__((ext_vector_type(4))) float f32x4;

#define KTOT 110592   // 4096*27
#define KS2  64       // conv K-split blocks
#define KCH  1728     // KTOT/KS2
#define NIT  54       // KCH/32

__device__ __forceinline__ unsigned short f2bf(float f) {
  unsigned int u = __float_as_uint(f);
  unsigned int r = u + 0x7FFFu + ((u >> 16) & 1u);
  return (unsigned short)(r >> 16);
}
__device__ __forceinline__ float bf2f(unsigned short u) {
  return __uint_as_float((unsigned int)u << 16);
}
__device__ __forceinline__ float wred_sum(float v) {
#pragma unroll
  for (int m = 32; m > 0; m >>= 1) v += __shfl_xor(v, m, 64);
  return v;
}
__device__ __forceinline__ float wred_max(float v) {
#pragma unroll
  for (int m = 32; m > 0; m >>= 1) v = fmaxf(v, __shfl_xor(v, m, 64));
  return v;
}
__device__ __forceinline__ void gld16(const void* g, void* l) {
  __builtin_amdgcn_global_load_lds((const __attribute__((address_space(1))) void*)g,
                                   (__attribute__((address_space(3))) void*)l, 16, 0, 0);
}

// ---------- K0: FUSED dwt (blocks 0..107) + weight transposes (blocks 108..299) (r20) ----------
__global__ __launch_bounds__(256) void k_front2(const float* __restrict__ x,
                                                const float* __restrict__ qkvw,
                                                const float* __restrict__ pw,
                                                float* __restrict__ xd,
                                                unsigned short* __restrict__ qwT,
                                                unsigned short* __restrict__ pwT) {
  __shared__ float tile[64][68];
  int t = threadIdx.x;
  int bid = blockIdx.x;

  if (bid < 108) {
    int b = bid / 27, p = bid % 27;
    int pd = p / 9, ph = (p / 3) % 3, pw3 = p % 3;
    const float s3 = 0.35355339059327373f;
#pragma unroll
    for (int cc = 0; cc < 2; cc++) {
      int c = t + cc * 256;
      const float* xb = x + (size_t)b * 216 * 512 + c;
#define XL(ed, eh, ew) xb[((2 * pd + (ed)) * 36 + (2 * ph + (eh)) * 6 + (2 * pw3 + (ew))) * 512]
      float v000 = XL(0, 0, 0), v001 = XL(0, 0, 1), v010 = XL(0, 1, 0), v011 = XL(0, 1, 1);
      float v100 = XL(1, 0, 0), v101 = XL(1, 0, 1), v110 = XL(1, 1, 0), v111 = XL(1, 1, 1);
#undef XL
      float lo00 = v000 + v001, hi00 = v000 - v001;
      float lo01 = v010 + v011, hi01 = v010 - v011;
      float lo10 = v100 + v101, hi10 = v100 - v101;
      float lo11 = v110 + v111, hi11 = v110 - v111;
      float ll0 = lo00 + lo01, lh0 = hi00 + hi01, hl0 = lo00 - lo01, hh0 = hi00 - hi01;
      float ll1 = lo10 + lo11, lh1 = hi10 + hi11, hl1 = lo10 - lo11, hh1 = hi10 - hi11;
      size_t base = (size_t)b * 110592 + (size_t)c * 27 + p;
      xd[base + 0 * 13824] = (ll0 + ll1) * s3;
      xd[base + 1 * 13824] = (lh0 + lh1) * s3;
      xd[base + 2 * 13824] = (hl0 + hl1) * s3;
      xd[base + 3 * 13824] = (hh0 + hh1) * s3;
      xd[base + 4 * 13824] = (ll0 - ll1) * s3;
      xd[base + 5 * 13824] = (lh0 - lh1) * s3;
      xd[base + 6 * 13824] = (hl0 - hl1) * s3;
      xd[base + 7 * 13824] = (hh0 - hh1) * s3;
    }
    return;
  }

  int idx = bid - 108;
  int bx = idx % 24;
  int n0 = (idx / 24) * 64;
  const float* src;
  unsigned short* dst;
  int rs, K, k0;
  if (bx < 8) { src = qkvw; dst = qwT; rs = 1536; K = 512; k0 = bx * 64; }
  else        { src = pw;   dst = pwT; rs = 512;  K = 1024; k0 = (bx - 8) * 64; }
  int kr = t >> 4, n4 = (t & 15) * 4;
#pragma unroll
  for (int i = 0; i < 4; i++) {
    int k = kr + i * 16;
    float4 v = *(const float4*)&src[(size_t)(k0 + k) * rs + n0 + n4];
    *(float4*)&tile[k][n4] = v;
  }
  __syncthreads();
  int nr = t >> 4, k4 = (t & 15) * 4;
#pragma unroll
  for (int i = 0; i < 4; i++) {
    int n = nr + i * 16;
    ushort4 o;
    o.x = f2bf(tile[k4 + 0][n]);
    o.y = f2bf(tile[k4 + 1][n]);
    o.z = f2bf(tile[k4 + 2][n]);
    o.w = f2bf(tile[k4 + 3][n]);
    *(ushort4*)&dst[(size_t)(n0 + n) * K + k0 + k4] = o;
  }
}

// ---------- K1: MFMA GEMM 64x64, 2-buffer pipelined (r20) ----------
__global__ __launch_bounds__(256) void k_gemm64(const float* __restrict__ A0,
                                                const float* __restrict__ A1,
                                                const unsigned short* __restrict__ BT,
                                                const float* __restrict__ bias,
                                                float* __restrict__ C, int K) {
  __shared__ __align__(16) unsigned short Ab[2][4096];
  __shared__ __align__(16) unsigned short Bb[2][4096];
  int t = threadIdx.x, l = t & 63, w = t >> 6;
  int wm = w & 1, wn = w >> 1;
  int n0 = blockIdx.x * 64, m0 = blockIdx.y * 64;
  int row = w * 16 + (l & 15);
  int kq = (l >> 4) * 8;
  int mg = m0 + row;
  bool mok = mg < 864;
  const unsigned short* pBt = BT + (size_t)(n0 + row) * K + kq;

#define GSTAGE(c, kk0)                                                      \
  do {                                                                      \
    gld16(pBt + (kk0), &Bb[c][t * 8]);                                      \
    gld16(pBt + (kk0) + 32, &Bb[c][2048 + t * 8]);                          \
    _Pragma("unroll") for (int s = 0; s < 2; s++) {                         \
      int ks = (kk0) + s * 32 + kq;                                         \
      float v[8] = {0.f, 0.f, 0.f, 0.f, 0.f, 0.f, 0.f, 0.f};                \
      if (mok) {                                                            \
        const float* sp = (ks < 512) ? (A0 + (size_t)mg * 512 + ks)         \
                                     : (A1 + (size_t)mg * 512 + (ks - 512));\
        float4 a = *(const float4*)sp;                                      \
        float4 b = *(const float4*)(sp + 4);                                \
        v[0] = a.x; v[1] = a.y; v[2] = a.z; v[3] = a.w;                     \
        v[4] = b.x; v[5] = b.y; v[6] = b.z; v[7] = b.w;                     \
      }                                                                     \
      union { unsigned short u[8]; bf16x8 h; } pk;                          \
      _Pragma("unroll") for (int e = 0; e < 8; e++) pk.u[e] = f2bf(v[e]);   \
      *(bf16x8*)&Ab[c][s * 2048 + t * 8] = pk.h;                            \
    }                                                                       \
  } while (0)

  f32x4 acc[2][2];
#pragma unroll
  for (int i = 0; i < 2; i++)
#pragma unroll
    for (int j = 0; j < 2; j++) acc[i][j] = (f32x4){0.f, 0.f, 0.f, 0.f};

  GSTAGE(0, 0);
  int cur = 0;
  for (int k0 = 0; k0 < K; k0 += 64) {
    __syncthreads();
    if (k0 + 64 < K) GSTAGE(cur ^ 1, k0 + 64);
#pragma unroll
    for (int kk = 0; kk < 2; kk++) {
      bf16x8 af[2], bf[2];
#pragma unroll
      for (int i = 0; i < 2; i++)
        af[i] = *(const bf16x8*)&Ab[cur][((kk * 4 + wm * 2 + i) * 64 + l) * 8];
#pragma unroll
      for (int j = 0; j < 2; j++)
        bf[j] = *(const bf16x8*)&Bb[cur][((kk * 4 + wn * 2 + j) * 64 + l) * 8];
#pragma unroll
      for (int i = 0; i < 2; i++)
#pragma unroll
        for (int j = 0; j < 2; j++)
          acc[i][j] = __builtin_amdgcn_mfma_f32_16x16x32_bf16(af[i], bf[j], acc[i][j], 0, 0, 0);
    }
    cur ^= 1;
  }
#undef GSTAGE
#pragma unroll
  for (int i = 0; i < 2; i++)
#pragma unroll
    for (int j = 0; j < 2; j++) {
      int n = n0 + wn * 32 + j * 16 + (l & 15);
      float bb = bias ? bias[n] : 0.f;
#pragma unroll
      for (int r = 0; r < 4; r++) {
        int m = m0 + wm * 32 + i * 16 + (l >> 4) * 4 + r;
        if (m < 864) C[(size_t)m * 512 + n] = acc[i][j][r] + bb;
      }
    }
}

// ---------- K3: im2col, 8 bf16 per thread (r8) ----------
__global__ __launch_bounds__(256) void k_im2col8(const float* __restrict__ xd,
                                                 unsigned short* __restrict__ A) {
  __shared__ int offtab[27];
  int m = blockIdx.y, t = threadIdx.x;
  if (m < 108 && t < 27) {
    int po = m % 27;
    int od = po / 9, oh = (po / 3) % 3, ow = po % 3;
    int kd = t / 9, kh = (t / 3) % 3, kw = t % 3;
    int id = od + kd - 1, ih = oh + kh - 1, iw = ow + kw - 1;
    offtab[t] = ((unsigned)id < 3u && (unsigned)ih < 3u && (unsigned)iw < 3u)
                    ? (id * 9 + ih * 3 + iw) : -1;
  }
  __syncthreads();
  int k0 = (blockIdx.x * 256 + t) * 8;
  union { unsigned short u[8]; uint4 q; } ov;
#pragma unroll
  for (int e = 0; e < 8; e++) ov.u[e] = 0;
  if (m < 108) {
    int b = m / 27;
    int ic = k0 / 27;
    int tt = k0 - ic * 27;
    const float* src = xd + ((size_t)b * 4096 + ic) * 27;
#pragma unroll
    for (int e = 0; e < 8; e++) {
      int o = offtab[tt];
      float v = (o >= 0) ? src[o] : 0.f;
      ov.u[e] = f2bf(v);
      if (++tt == 27) { tt = 0; src += 27; }
    }
  }
  *(uint4*)&A[(size_t)m * KTOT + k0] = ov.q;
}

// ---------- K4: FUSED conv4 + qgemm; conv partials stored as BF16 (r22 champion) ----------
__global__ __launch_bounds__(256, 2) void k_convq(const unsigned short* __restrict__ Ag,
                                                  const float* __restrict__ W,
                                                  unsigned short* __restrict__ fpart,
                                                  const float* __restrict__ x,
                                                  const unsigned short* __restrict__ qwT,
                                                  float* __restrict__ q) {
  __shared__ __align__(16) char smem[73728];
  int t = threadIdx.x, l = t & 63, w = t >> 6;
  int bid = blockIdx.x;

  if (bid >= 512) {
    unsigned short* Ab = (unsigned short*)smem;          // 8KB
    unsigned short* Bb = (unsigned short*)(smem + 8192); // 8KB
    int g = bid - 512;  // 0..111
    int n0 = (g & 7) * 64, m0 = (g >> 3) * 64;
    int wm = w & 1, wn = w >> 1;
    int row = w * 16 + (l & 15);
    int kq = (l >> 4) * 8;
    int mg = m0 + row;
    bool mok = mg < 864;
    const unsigned short* pBt = qwT + (size_t)(n0 + row) * 512 + kq;
    f32x4 acc[2][2];
#pragma unroll
    for (int i = 0; i < 2; i++)
#pragma unroll
      for (int j = 0; j < 2; j++) acc[i][j] = (f32x4){0.f, 0.f, 0.f, 0.f};
    for (int k0 = 0; k0 < 512; k0 += 64) {
      __syncthreads();
      gld16(pBt + k0, &Bb[t * 8]);
      gld16(pBt + k0 + 32, &Bb[2048 + t * 8]);
#pragma unroll
      for (int s = 0; s < 2; s++) {
        int ks = k0 + s * 32 + kq;
        float v[8] = {0.f, 0.f, 0.f, 0.f, 0.f, 0.f, 0.f, 0.f};
        if (mok) {
          const float* sp = x + (size_t)mg * 512 + ks;
          float4 a = *(const float4*)sp;
          float4 b = *(const float4*)(sp + 4);
          v[0] = a.x; v[1] = a.y; v[2] = a.z; v[3] = a.w;
          v[4] = b.x; v[5] = b.y; v[6] = b.z; v[7] = b.w;
        }
        union { unsigned short u[8]; bf16x8 h; } pk;
#pragma unroll
        for (int e = 0; e < 8; e++) pk.u[e] = f2bf(v[e]);
        *(bf16x8*)&Ab[s * 2048 + t * 8] = pk.h;
      }
      __syncthreads();
#pragma unroll
      for (int kk = 0; kk < 2; kk++) {
        bf16x8 af[2], bf[2];
#pragma unroll
        for (int i = 0; i < 2; i++)
          af[i] = *(const bf16x8*)&Ab[((kk * 4 + wm * 2 + i) * 64 + l) * 8];
#pragma unroll
        for (int j = 0; j < 2; j++)
          bf[j] = *(const bf16x8*)&Bb[((kk * 4 + wn * 2 + j) * 64 + l) * 8];
#pragma unroll
        for (int i = 0; i < 2; i++)
#pragma unroll
          for (int j = 0; j < 2; j++)
            acc[i][j] = __builtin_amdgcn_mfma_f32_16x16x32_bf16(af[i], bf[j], acc[i][j], 0, 0, 0);
      }
    }
#pragma unroll
    for (int i = 0; i < 2; i++)
#pragma unroll
      for (int j = 0; j < 2; j++) {
        int n = n0 + wn * 32 + j * 16 + (l & 15);
#pragma unroll
        for (int r = 0; r < 4; r++) {
          int m = m0 + wm * 32 + i * 16 + (l >> 4) * 4 + r;
          if (m < 864) q[(size_t)m * 512 + n] = acc[i][j][r];
        }
      }
    return;
  }

  typedef unsigned short (*AbufT)[4096];
  typedef float (*BbufT)[4096];
  AbufT Abuf = (AbufT)smem;            // 3 x 8KB = 24KB
  BbufT Bbuf = (BbufT)(smem + 24576);  // 3 x 16KB = 48KB
  int wm = w & 1, wn = w >> 1;
  int oc0 = (bid & 7) * 128;
  int ks = bid >> 3;
  int kbase = ks * KCH;
  int kq = (l >> 4) * 8;

  const unsigned short* pA0 = Ag + (size_t)(w * 16 + (l & 15)) * KTOT + kbase + kq;
  const unsigned short* pA1 = Ag + (size_t)((w + 4) * 16 + (l & 15)) * KTOT + kbase + kq;
  const float* pB0 = W + (size_t)(oc0 + w * 16 + (l & 15)) * KTOT + kbase + kq;
  const float* pB1 = W + (size_t)(oc0 + (w + 4) * 16 + (l & 15)) * KTOT + kbase + kq;
  const float* pB2 = pB0 + 4;
  const float* pB3 = pB1 + 4;

#define STG(c, s)                                   \
  do {                                              \
    int ko = (s) * 32;                              \
    gld16(pA0 + ko, &Abuf[c][t * 8]);               \
    gld16(pA1 + ko, &Abuf[c][2048 + t * 8]);        \
    gld16(pB0 + ko, &Bbuf[c][t * 4]);               \
    gld16(pB1 + ko, &Bbuf[c][1024 + t * 4]);        \
    gld16(pB2 + ko, &Bbuf[c][2048 + t * 4]);        \
    gld16(pB3 + ko, &Bbuf[c][3072 + t * 4]);        \
  } while (0)

  f32x4 acc[4][4];
#pragma unroll
  for (int i = 0; i < 4; i++)
#pragma unroll
    for (int j = 0; j < 4; j++) acc[i][j] = (f32x4){0.f, 0.f, 0.f, 0.f};

#define CMP(c)                                                                     \
  do {                                                                             \
    bf16x8 av[4];                                                                  \
    _Pragma("unroll") for (int i = 0; i < 4; i++)                                  \
        av[i] = *(const bf16x8*)&Abuf[c][((wm * 4 + i) * 64 + l) * 8];             \
    bf16x8 bv[4];                                                                  \
    _Pragma("unroll") for (int j = 0; j < 4; j++) {                                \
      f32x4 lo = *(const f32x4*)&Bbuf[c][((wn * 4 + j) * 64 + l) * 4];             \
      f32x4 hi = *(const f32x4*)&Bbuf[c][2048 + ((wn * 4 + j) * 64 + l) * 4];      \
      union { unsigned short u[8]; bf16x8 h; } pk;                                 \
      _Pragma("unroll") for (int e = 0; e < 4; e++) {                              \
        pk.u[e] = f2bf(lo[e]); pk.u[4 + e] = f2bf(hi[e]);                          \
      }                                                                            \
      bv[j] = pk.h;                                                                \
    }                                                                              \
    _Pragma("unroll") for (int i = 0; i < 4; i++)                                  \
        _Pragma("unroll") for (int j = 0; j < 4; j++)                              \
            acc[i][j] = __builtin_amdgcn_mfma_f32_16x16x32_bf16(av[i], bv[j],      \
                                                                acc[i][j], 0, 0, 0); \
  } while (0)

#define WAIT6 asm volatile("s_waitcnt vmcnt(6)" ::: "memory")
#define WAIT0 asm volatile("s_waitcnt vmcnt(0)" ::: "memory")

  STG(0, 0);
  STG(1, 1);
  int s = 2;
#pragma unroll 1
  for (int g = 0; g < 17; g++) {  // iters m = 0..50
    WAIT6; __builtin_amdgcn_s_barrier(); STG(2, s); CMP(0); s++;
    WAIT6; __builtin_amdgcn_s_barrier(); STG(0, s); CMP(1); s++;
    WAIT6; __builtin_amdgcn_s_barrier(); STG(1, s); CMP(2); s++;
  }
  WAIT6; __builtin_amdgcn_s_barrier(); STG(2, 53); CMP(0);
  WAIT6; __builtin_amdgcn_s_barrier(); CMP(1);
  WAIT0; __builtin_amdgcn_s_barrier(); CMP(2);
#undef STG
#undef CMP
#undef WAIT6
#undef WAIT0

  int mbase = wm * 64 + (l >> 4) * 4;
  int obase = oc0 + wn * 64 + (l & 15);
#pragma unroll
  for (int i = 0; i < 4; i++) {
    int m = mbase + i * 16;
#pragma unroll
    for (int j = 0; j < 4; j++) {
      int oc = obase + j * 16;
      unsigned short* dst = fpart + ((size_t)ks * 128 + m) * 1024 + oc;
      dst[0] = f2bf(acc[i][j][0]);
      dst[1024] = f2bf(acc[i][j][1]);
      dst[2048] = f2bf(acc[i][j][2]);
      dst[3072] = f2bf(acc[i][j][3]);
    }
  }
}

// ---------- K5a: reduce bf16 K-split + bias + BN + ReLU -> f (B,1024,27) ----------
__global__ __launch_bounds__(256) void k_bnrelu(const unsigned short* __restrict__ fpart,
                                                const float* __restrict__ convb,
                                                const float* __restrict__ bng,
                                                const float* __restrict__ bnb,
                                                const float* __restrict__ bnm,
                                                const float* __restrict__ bnv,
                                                float* __restrict__ f) {
  int ch = blockIdx.x * 256 + threadIdx.x;
  int m = blockIdx.y;
  if (m >= 108) return;
  float s = 0.f;
#pragma unroll 8
  for (int ks = 0; ks < KS2; ks++) s += bf2f(fpart[((size_t)ks * 128 + m) * 1024 + ch]);
  float gs = bng[ch] * rsqrtf(bnv[ch] + 1e-5f);
  float bb = (convb[ch] - bnm[ch]) * gs + bnb[ch];
  float r = fmaxf(s * gs + bb, 0.f);
  int b = m / 27, p = m % 27;
  f[((size_t)b * 1024 + ch) * 27 + p] = r;
}

// ---------- K5b: LayerNorm(27) + kv GEMM + scatter kT, v as BF16 (r19) ----------
__global__ __launch_bounds__(256) void k_lnkv(const float* __restrict__ f,
                                              const float* __restrict__ lng,
                                              const float* __restrict__ lnb,
                                              const float* __restrict__ kvw,
                                              const float* __restrict__ kvb,
                                              unsigned short* __restrict__ kT,
                                              unsigned short* __restrict__ vbuf) {
  __shared__ float g_s[4][28];
  int t = threadIdx.x, w = t >> 6, l = t & 63;
  int row = blockIdx.x * 4 + w;
  int b = row >> 10, ch = row & 1023;
  float val = 0.f;
  if (l < 27) val = f[((size_t)b * 1024 + ch) * 27 + l];
  float x1 = (l < 27) ? val : 0.f;
  float sum = wred_sum(x1);
  float sumsq = wred_sum(x1 * x1);
  float mu = sum * (1.f / 27.f);
  float var = sumsq * (1.f / 27.f) - mu * mu;
  float inv = rsqrtf(var + 1e-5f);
  if (l < 27) g_s[w][l] = (val - mu) * inv * lng[l] + lnb[l];
  __syncthreads();
#pragma unroll
  for (int j = 0; j < 4; j++) {
    int y = j * 64 + l;
    if (y < 216) {
      float acc = kvb[y];
#pragma unroll
      for (int p = 0; p < 27; p++) acc = fmaf(g_s[w][p], kvw[p * 216 + y], acc);
      int cc = ch & 511;
      int flat = cc * 216 + y;
      int n = flat >> 9, hd = flat & 511, h = hd >> 6, d = hd & 63;
      if (ch < 512)
        kT[(((size_t)b * 8 + h) * 64 + d) * 216 + n] = f2bf(acc);
      else
        vbuf[(((size_t)b * 8 + h) * 216 + n) * 64 + d] = f2bf(acc);
    }
  }
}

// ---------- K6: cross-attention, LDS-staged K/V per (b,h) (r21 champion) ----------
__global__ __launch_bounds__(256, 2) void k_attn2(const float* __restrict__ q,
                                                  const unsigned short* __restrict__ kT,
                                                  const unsigned short* __restrict__ vbuf,
                                                  float* __restrict__ o) {
  __shared__ __align__(16) unsigned short ks_s[13824];
  __shared__ __align__(16) unsigned short vs_s[13824];
  __shared__ float q_s[4][64];
  __shared__ float p_s[4][224];
  int t = threadIdx.x, w = t >> 6, l = t & 63;
  int bid = blockIdx.x;
  int b = bid >> 7, h = (bid >> 4) & 7, part = bid & 15;
  int r0 = part * 14;
  const unsigned short* kb = kT + ((size_t)b * 8 + h) * 13824;
  const unsigned short* vb = vbuf + ((size_t)b * 8 + h) * 13824;
  for (int i = t; i < 1728; i += 256) {
    ((uint4*)ks_s)[i] = ((const uint4*)kb)[i];
    ((uint4*)vs_s)[i] = ((const uint4*)vb)[i];
  }
  __syncthreads();
#pragma unroll 1
  for (int it = 0; it < 4; it++) {
    int r = it * 4 + w;
    int n = r0 + r;
    if (r >= 14 || n >= 216) break;
    q_s[w][l] = q[((size_t)b * 216 + n) * 512 + h * 64 + l];
    float sc[4];
#pragma unroll
    for (int j = 0; j < 4; j++) {
      int y = j * 64 + l;
      float s = -1e30f;
      if (y < 216) {
        s = 0.f;
#pragma unroll 8
        for (int d = 0; d < 64; d++) s = fmaf(q_s[w][d], bf2f(ks_s[d * 216 + y]), s);
        s *= 0.125f;
      }
      sc[j] = s;
    }
    float mx = fmaxf(fmaxf(sc[0], sc[1]), fmaxf(sc[2], sc[3]));
    mx = wred_max(mx);
    float e0 = (sc[0] > -1e29f) ? __expf(sc[0] - mx) : 0.f;
    float e1 = (sc[1] > -1e29f) ? __expf(sc[1] - mx) : 0.f;
    float e2 = (sc[2] > -1e29f) ? __expf(sc[2] - mx) : 0.f;
    float e3 = (sc[3] > -1e29f) ? __expf(sc[3] - mx) : 0.f;
    float sum = wred_sum(e0 + e1 + e2 + e3);
    float inv = 1.f / sum;
    if (l < 216) p_s[w][l] = e0 * inv;
    if (64 + l < 216) p_s[w][64 + l] = e1 * inv;
    if (128 + l < 216) p_s[w][128 + l] = e2 * inv;
    if (192 + l < 216) p_s[w][192 + l] = e3 * inv;
    float a0 = 0.f, a1 = 0.f;
#pragma unroll 4
    for (int y = 0; y < 216; y += 2) {
      a0 = fmaf(p_s[w][y + 0], bf2f(vs_s[(y + 0) * 64 + l]), a0);
      a1 = fmaf(p_s[w][y + 1], bf2f(vs_s[(y + 1) * 64 + l]), a1);
    }
    o[((size_t)b * 216 + n) * 512 + h * 64 + l] = a0 + a1;
  }
}

extern "C" void kernel_launch(void* const* d_in, const int* in_sizes, int n_in,
                              void* d_out, int out_size, void* d_ws, size_t ws_size,
                              hipStream_t stream) {
  const float* x = (const float*)d_in[0];
  const float* qkvw = (const float*)d_in[1];
  const float* convw = (const float*)d_in[2];
  const float* convb = (const float*)d_in[3];
  const float* bng = (const float*)d_in[4];
  const float* bnb = (const float*)d_in[5];
  const float* bnm = (const float*)d_in[6];
  const float* bnv = (const float*)d_in[7];
  const float* lng = (const float*)d_in[8];
  const float* lnb = (const float*)d_in[9];
  const float* kvw = (const float*)d_in[10];
  const float* kvb = (const float*)d_in[11];
  const float* pw = (const float*)d_in[12];
  const float* pb = (const float*)d_in[13];
  float* out = (float*)d_out;

  char* ws = (char*)d_ws;
  float* q = (float*)(ws + 0);                              // 1,769,472
  float* xd = (float*)(ws + 1769472);                       // 1,769,472
  unsigned short* A = (unsigned short*)(ws + 3538944);      // 28,311,552
  unsigned short* fpart = (unsigned short*)(ws + 31850496); // 16,777,216 (bf16)
  float* f = (float*)(ws + 48627712);                       // 442,368
  unsigned short* kT = (unsigned short*)(ws + 49070080);    // 884,736 (bf16)
  unsigned short* vbuf = (unsigned short*)(ws + 49954816);  // 884,736 (bf16)
  float* o = (float*)(ws + 50839552);                       // 1,769,472
  unsigned short* qwT = (unsigned short*)(ws + 52609024);   // 524,288
  unsigned short* pwT = (unsigned short*)(ws + 53133312);   // 1,048,576

  k_front2<<<300, 256, 0, stream>>>(x, qkvw, pw, xd, qwT, pwT);
  k_im2col8<<<dim3(54, 128), 256, 0, stream>>>(xd, A);
  k_convq<<<624, 256, 0, stream>>>(A, convw, fpart, x, qwT, q);
  k_bnrelu<<<dim3(4, 128), 256, 0, stream>>>(fpart, convb, bng, bnb, bnm, bnv, f);
  k_lnkv<<<1024, 256, 0, stream>>>(f, lng, lnb, kvw, kvb, kT, vbuf);
  k_attn2<<<512, 256, 0, stream>>>(q, kT, vbuf, o);
  k_gemm64<<<dim3(8, 14), 256, 0, stream>>>(o, x, pwT, pb, out, 1024);
}